// Round 1
// 232.374 us; speedup vs baseline: 1.0239x; 1.0239x over previous
//
#include <hip/hip_runtime.h>
#include <math.h>
#include <stdint.h>

#define N512 512

typedef __attribute__((ext_vector_type(8))) short short8;
typedef __attribute__((ext_vector_type(4))) float floatx4;

#define VMCNT(n) asm volatile("s_waitcnt vmcnt(" #n ")" ::: "memory")
#define LGKM0    asm volatile("s_waitcnt lgkmcnt(0)" ::: "memory")
#define FENCE    asm volatile("" ::: "memory")
#define BARRIER  __builtin_amdgcn_s_barrier()

__device__ __forceinline__ short f2bf(float f) {
    uint32_t u = __float_as_uint(f);
    uint32_t r = u + 0x7fffu + ((u >> 16) & 1u);
    return (short)(r >> 16);
}

// cheap round-half-up (2 VALU): fine vs 0.109 threshold
__device__ __forceinline__ short f2bf_fast(float f) {
    return (short)((__float_as_uint(f) + 0x8000u) >> 16);
}

__device__ __forceinline__ void gload_lds16(const void* g, void* l) {
    __builtin_amdgcn_global_load_lds(
        (const __attribute__((address_space(1))) void*)g,
        (__attribute__((address_space(3))) void*)l,
        16, 0, 0);
}

// M[n,k] = s_k * cos(pi * k * (2n+1) / (2N)), bf16 (RNE-ish)
__global__ __launch_bounds__(256) void build_idct_matrix_bf16(short* __restrict__ M) {
    int idx = blockIdx.x * 256 + threadIdx.x;
    int n = idx >> 9;
    int k = idx & 511;
    int j = (k * (2 * n + 1)) & (4 * N512 - 1);
    float theta = (float)j * (3.14159265358979323846f / (2.0f * (float)N512));
    float s = (k == 0) ? 0.044194173824159216f : 0.0625f;
    M[idx] = f2bf(s * cosf(theta));
}

// ---------------------------------------------------------------------------
// Stage 1 (fused cvt), 2-phase double-buffered pipeline:
//   Tt[z][n][h] = sum_k M[n,k] * X[z][h,k]
// A = M bf16 via global_load_lds(16B, XOR swizzle) -> LDS (DMA).
// B = X fp32 loaded coalesced float4 into regs (issued one tile EARLY),
//     cvt to bf16 + swizzled ds_write AFTER the compute barrier (T14 split).
// Raw s_barrier + counted vmcnt: next tile's 12 loads stay in flight across
// the barrier; the loop-head vmcnt(12) drains exactly the previous tile.
// 128x128 tile, BK=64, 4 waves, each 4x4 of 16x16x32 bf16 MFMA.
// ---------------------------------------------------------------------------
__global__ __launch_bounds__(256) void gemm_s1(const short* __restrict__ A,
                                               const float* __restrict__ Xg,
                                               short* __restrict__ Tg) {
    // double buffer: buf b at b*16384 shorts; A tile 8192 | B tile 8192
    __shared__ __align__(16) short lds[4 * 8192];

    const int t = threadIdx.x;
    const int w = t >> 6;          // wave 0..3
    const int l = t & 63;
    const int q = (t >> 4) & 3;    // quad in wave
    const int r = t & 15;

    const int bm0 = blockIdx.y * 128;   // A rows (n)
    const int bn0 = blockIdx.x * 128;   // B rows (h)
    const int wm0 = (w >> 1) * 64;
    const int wn0 = (w & 1) * 64;

    const float* Xs = Xg + ((long)blockIdx.z << 18);
    short* Tt = Tg + ((long)blockIdx.z << 18);

    // A staging: instr i of wave w covers tile rows (w*4+i)*8 .. +7
    const int rsub = l >> 3;                 // row within 8-row chunk
    const int glog = (l & 7) ^ rsub;         // swizzled 16B-group to fetch

    // B staging: pass p: row rt = p*16 + (t>>4); float4 at col (t&15)*4
    const int brow = t >> 4;                 // 0..15 (row within pass)
    const int col4 = t & 15;                 // float4 index in row
    const int bg   = col4 >> 1;              // 8-float group 0..7
    const int bh   = col4 & 1;               // half of group

    floatx4 acc[4][4] = {};
    float4 v[8];

    // ---- prologue: stage tile 0 ----
#pragma unroll
    for (int p = 0; p < 8; ++p) {
        const int rt = p * 16 + brow;
        v[p] = *(const float4*)(Xs + (((long)(bn0 + rt)) << 9) + col4 * 4);
    }
#pragma unroll
    for (int i = 0; i < 4; ++i) {
        const int chunk = w * 4 + i;
        const int rt = chunk * 8 + rsub;
        gload_lds16(A + (((long)(bm0 + rt)) << 9) + glog * 8,
                    lds + chunk * 512);                     // bufA0
    }
    VMCNT(4);   // B(0) regs ready (A-dma may remain in flight)
#pragma unroll
    for (int p = 0; p < 8; ++p) {
        const int rt = p * 16 + brow;
        const int bchunk = rt >> 3;
        const int brs = rt & 7;
        short4 o;
        o.x = f2bf_fast(v[p].x);
        o.y = f2bf_fast(v[p].y);
        o.z = f2bf_fast(v[p].z);
        o.w = f2bf_fast(v[p].w);
        *(short4*)(lds + 8192 + bchunk * 512 + brs * 64 + ((bg ^ brs) * 8) + bh * 4) = o;
    }
    LGKM0;

    for (int kt = 0; kt < 8; ++kt) {
        short* bufc = lds + (kt & 1) * 16384;
        short* bufn = lds + ((kt + 1) & 1) * 16384;

        if (kt < 7) {
            const int k0n = (kt + 1) * 64;
            // issue next B reg-loads (8 vm) + next A dma (4 vm)
#pragma unroll
            for (int p = 0; p < 8; ++p) {
                const int rt = p * 16 + brow;
                v[p] = *(const float4*)(Xs + (((long)(bn0 + rt)) << 9) + k0n + col4 * 4);
            }
#pragma unroll
            for (int i = 0; i < 4; ++i) {
                const int chunk = w * 4 + i;
                const int rt = chunk * 8 + rsub;
                gload_lds16(A + (((long)(bm0 + rt)) << 9) + k0n + glog * 8,
                            bufn + chunk * 512);
            }
            VMCNT(12);   // drain everything older than this iter's 12 issues
        } else {
            VMCNT(0);
        }
        BARRIER;         // bufc (A dma + B writes) visible to all waves
        FENCE;

        {
            short* ldsA = bufc;
            short* ldsB = bufc + 8192;
#pragma unroll
            for (int kk = 0; kk < 2; ++kk) {
                const int c = kk * 4 + q;
                const int goff = ((c ^ (r & 7)) * 8);
                short8 af[4], bfr[4];
#pragma unroll
                for (int i = 0; i < 4; ++i) {
                    af[i]  = *(const short8*)(ldsA + (wm0 + i * 16 + r) * 64 + goff);
                    bfr[i] = *(const short8*)(ldsB + (wn0 + i * 16 + r) * 64 + goff);
                }
#pragma unroll
                for (int i = 0; i < 4; ++i)
#pragma unroll
                    for (int j = 0; j < 4; ++j)
                        acc[i][j] = __builtin_amdgcn_mfma_f32_16x16x32_bf16(
                            af[i], bfr[j], acc[i][j], 0, 0, 0);
            }
        }

        FENCE;           // keep ds_reads above this barrier
        BARRIER;         // all waves done reading bufc; safe to overwrite next iter

        if (kt < 7) {
            VMCNT(4);    // next-tile B regs ready (next A-dma may remain)
#pragma unroll
            for (int p = 0; p < 8; ++p) {
                const int rt = p * 16 + brow;
                const int bchunk = rt >> 3;
                const int brs = rt & 7;
                short4 o;
                o.x = f2bf_fast(v[p].x);
                o.y = f2bf_fast(v[p].y);
                o.z = f2bf_fast(v[p].z);
                o.w = f2bf_fast(v[p].w);
                *(short4*)(bufn + 8192 + bchunk * 512 + brs * 64 + ((bg ^ brs) * 8) + bh * 4) = o;
            }
            LGKM0;       // ds_writes landed before next iter's barrier
        }
    }

    // epilogue: D row = quad*4+reg, col = lane&15 (bf16 out)
#pragma unroll
    for (int i = 0; i < 4; ++i) {
        const int mrow = bm0 + wm0 + i * 16 + q * 4;
#pragma unroll
        for (int j = 0; j < 4; ++j) {
            const int ncol = bn0 + wn0 + j * 16 + r;
#pragma unroll
            for (int rg = 0; rg < 4; ++rg)
                Tt[(long)(mrow + rg) * N512 + ncol] = f2bf(acc[i][j][rg]);
        }
    }
}

// ---------------------------------------------------------------------------
// Stage 2: Out[z][m][n] = sum_h M[m,h] * Tt[z][n,h]  (both bf16, fp32 out)
// Same 2-phase dbuf pipeline; both operands via global_load_lds DMA.
// ---------------------------------------------------------------------------
__global__ __launch_bounds__(256) void gemm_s2(const short* __restrict__ A,
                                               const short* __restrict__ Bg,
                                               float* __restrict__ Cg) {
    __shared__ __align__(16) short lds[4 * 8192];

    const int t = threadIdx.x;
    const int w = t >> 6;
    const int l = t & 63;
    const int q = (t >> 4) & 3;
    const int r = t & 15;

    const int bm0 = blockIdx.y * 128;
    const int bn0 = blockIdx.x * 128;
    const int wm0 = (w >> 1) * 64;
    const int wn0 = (w & 1) * 64;

    const short* Bs = Bg + ((long)blockIdx.z << 18);
    float* C = Cg + ((long)blockIdx.z << 18);

    const int rsub = l >> 3;
    const int glog = (l & 7) ^ rsub;

    floatx4 acc[4][4] = {};

    // ---- prologue: stage tile 0 (8 dma) ----
#pragma unroll
    for (int i = 0; i < 4; ++i) {
        const int chunk = w * 4 + i;
        const int rt = chunk * 8 + rsub;
        gload_lds16(A + (((long)(bm0 + rt)) << 9) + glog * 8,
                    lds + chunk * 512);
        gload_lds16(Bs + (((long)(bn0 + rt)) << 9) + glog * 8,
                    lds + 8192 + chunk * 512);
    }

    for (int kt = 0; kt < 8; ++kt) {
        short* bufc = lds + (kt & 1) * 16384;
        short* bufn = lds + ((kt + 1) & 1) * 16384;

        if (kt < 7) {
            const int k0n = (kt + 1) * 64;
#pragma unroll
            for (int i = 0; i < 4; ++i) {
                const int chunk = w * 4 + i;
                const int rt = chunk * 8 + rsub;
                gload_lds16(A + (((long)(bm0 + rt)) << 9) + k0n + glog * 8,
                            bufn + chunk * 512);
                gload_lds16(Bs + (((long)(bn0 + rt)) << 9) + k0n + glog * 8,
                            bufn + 8192 + chunk * 512);
            }
            VMCNT(8);    // drain previous tile's dma; this iter's 8 stay in flight
        } else {
            VMCNT(0);
        }
        BARRIER;
        FENCE;

        {
            short* ldsA = bufc;
            short* ldsB = bufc + 8192;
#pragma unroll
            for (int kk = 0; kk < 2; ++kk) {
                const int c = kk * 4 + q;
                const int goff = ((c ^ (r & 7)) * 8);
                short8 af[4], bfr[4];
#pragma unroll
                for (int i = 0; i < 4; ++i) {
                    af[i]  = *(const short8*)(ldsA + (wm0 + i * 16 + r) * 64 + goff);
                    bfr[i] = *(const short8*)(ldsB + (wn0 + i * 16 + r) * 64 + goff);
                }
#pragma unroll
                for (int i = 0; i < 4; ++i)
#pragma unroll
                    for (int j = 0; j < 4; ++j)
                        acc[i][j] = __builtin_amdgcn_mfma_f32_16x16x32_bf16(
                            af[i], bfr[j], acc[i][j], 0, 0, 0);
            }
        }

        FENCE;
        BARRIER;
    }

#pragma unroll
    for (int i = 0; i < 4; ++i) {
        const int mrow = bm0 + wm0 + i * 16 + q * 4;
#pragma unroll
        for (int j = 0; j < 4; ++j) {
            const int ncol = bn0 + wn0 + j * 16 + r;
#pragma unroll
            for (int rg = 0; rg < 4; ++rg)
                C[(long)(mrow + rg) * N512 + ncol] = acc[i][j][rg];
        }
    }
}

extern "C" void kernel_launch(void* const* d_in, const int* in_sizes, int n_in,
                              void* d_out, int out_size, void* d_ws, size_t ws_size,
                              hipStream_t stream) {
    const float* X = (const float*)d_in[0];
    float* out = (float*)d_out;

    const long plane = (long)N512 * N512;          // 262144
    const int slices = in_sizes[0] / (int)plane;   // 96

    short* Mb = (short*)d_ws;                      // 512 KB
    short* Tt = Mb + plane;                        // chunk * plane bf16

    long avail = (long)ws_size - plane * 2;        // bytes after M
    int chunk = (int)(avail / (plane * 2));        // bf16 plane per slice
    if (chunk > slices) chunk = slices;
    // snap to multiple of 32: grid = 16 blocks/z; 2 blocks/CU resident ->
    // 512-block scheduling waves; 32|chunk keeps every wave exactly full.
    if (chunk >= 32) chunk &= ~31;
    if (chunk < 1) chunk = 1;

    build_idct_matrix_bf16<<<dim3((int)(plane / 256)), dim3(256), 0, stream>>>(Mb);

    for (int s0 = 0; s0 < slices; s0 += chunk) {
        int c = (s0 + chunk <= slices) ? chunk : (slices - s0);
        // stage 1 (reads fp32 X directly): Tt[z][n][h] = sum_k M[n,k]*X[z][h,k]
        gemm_s1<<<dim3(4, 4, c), dim3(256), 0, stream>>>(
            Mb, X + (long)s0 * plane, Tt);
        // stage 2: Out[z][m][n] = sum_h M[m,h]*Tt[z][n,h]
        gemm_s2<<<dim3(4, 4, c), dim3(256), 0, stream>>>(
            Mb, Tt, out + (long)s0 * plane);
    }
}

// Round 2
// 230.711 us; speedup vs baseline: 1.0313x; 1.0072x over previous
//
#include <hip/hip_runtime.h>
#include <math.h>
#include <stdint.h>

#define N512 512

typedef __attribute__((ext_vector_type(8))) short short8;
typedef __attribute__((ext_vector_type(4))) float floatx4;

#define VMCNT(n) asm volatile("s_waitcnt vmcnt(" #n ")" ::: "memory")
#define LGKM0    asm volatile("s_waitcnt lgkmcnt(0)" ::: "memory")
#define FENCE    asm volatile("" ::: "memory")
#define BARRIER  __builtin_amdgcn_s_barrier()

__device__ __forceinline__ short f2bf(float f) {
    uint32_t u = __float_as_uint(f);
    uint32_t r = u + 0x7fffu + ((u >> 16) & 1u);
    return (short)(r >> 16);
}

// cheap round-half-up (2 VALU): fine vs 0.109 threshold
__device__ __forceinline__ short f2bf_fast(float f) {
    return (short)((__float_as_uint(f) + 0x8000u) >> 16);
}

__device__ __forceinline__ void gload_lds16(const void* g, void* l) {
    __builtin_amdgcn_global_load_lds(
        (const __attribute__((address_space(1))) void*)g,
        (__attribute__((address_space(3))) void*)l,
        16, 0, 0);
}

// XCD-sibling decode: per 32 consecutive linear ids = 8 (x,z) tiles x 4 y.
// y-siblings (which share the X B-tile) sit 8 apart -> same XCD under the
// HW's round-robin id->XCD map -> B-tile fetched once per L2.
// Falls back to plain decode when nz is odd (tail safety).
__device__ __forceinline__ void decode_swz(int L, int nz,
                                           int& bx, int& by, int& bz) {
    if (nz & 1) {
        bx = L & 3; by = (L >> 2) & 3; bz = L >> 4;
    } else {
        const int g = L >> 5, s = L & 31;
        const int u = (g << 3) | (s & 7);
        by = s >> 3; bx = u & 3; bz = u >> 2;
    }
}

// M[n,k] = s_k * cos(pi * k * (2n+1) / (2N)), bf16 (RNE-ish)
__global__ __launch_bounds__(256) void build_idct_matrix_bf16(short* __restrict__ M) {
    int idx = blockIdx.x * 256 + threadIdx.x;
    int n = idx >> 9;
    int k = idx & 511;
    int j = (k * (2 * n + 1)) & (4 * N512 - 1);
    float theta = (float)j * (3.14159265358979323846f / (2.0f * (float)N512));
    float s = (k == 0) ? 0.044194173824159216f : 0.0625f;
    M[idx] = f2bf(s * cosf(theta));
}

// ---------------------------------------------------------------------------
// Stage 1 (fused cvt), 2-phase double-buffered pipeline:
//   Tt[z][n][h] = sum_k M[n,k] * X[z][h,k]
// A = M bf16 via global_load_lds(16B, XOR swizzle) -> LDS (DMA).
// B = X fp32 loaded coalesced float4 into regs (issued one tile EARLY),
//     cvt to bf16 + swizzled ds_write AFTER the compute barrier (T14 split).
// Epilogue: C tile staged through LDS -> 256B-contiguous coalesced stores
// (direct 32B bf16 segments caused RMW: WRITE x3 + RMW fetches).
// ---------------------------------------------------------------------------
__global__ __launch_bounds__(256) void gemm_s1(const short* __restrict__ A,
                                               const float* __restrict__ Xg,
                                               short* __restrict__ Tg) {
    // double buffer: buf b at b*16384 shorts; A tile 8192 | B tile 8192
    __shared__ __align__(16) short lds[4 * 8192];

    const int t = threadIdx.x;
    const int w = t >> 6;          // wave 0..3
    const int l = t & 63;
    const int q = (t >> 4) & 3;    // quad in wave
    const int r = t & 15;

    int bx, by, bz;
    decode_swz(blockIdx.x, (int)gridDim.x >> 4, bx, by, bz);

    const int bm0 = by * 128;   // A rows (n)
    const int bn0 = bx * 128;   // B rows (h)
    const int wm0 = (w >> 1) * 64;
    const int wn0 = (w & 1) * 64;

    const float* Xs = Xg + ((long)bz << 18);
    short* Tt = Tg + ((long)bz << 18);

    // A staging: instr i of wave w covers tile rows (w*4+i)*8 .. +7
    const int rsub = l >> 3;                 // row within 8-row chunk
    const int glog = (l & 7) ^ rsub;         // swizzled 16B-group to fetch

    // B staging: pass p: row rt = p*16 + (t>>4); float4 at col (t&15)*4
    const int brow = t >> 4;                 // 0..15 (row within pass)
    const int col4 = t & 15;                 // float4 index in row
    const int bg   = col4 >> 1;              // 8-float group 0..7
    const int bh   = col4 & 1;               // half of group

    floatx4 acc[4][4] = {};
    float4 v[8];

    // ---- prologue: stage tile 0 ----
#pragma unroll
    for (int p = 0; p < 8; ++p) {
        const int rt = p * 16 + brow;
        v[p] = *(const float4*)(Xs + (((long)(bn0 + rt)) << 9) + col4 * 4);
    }
#pragma unroll
    for (int i = 0; i < 4; ++i) {
        const int chunk = w * 4 + i;
        const int rt = chunk * 8 + rsub;
        gload_lds16(A + (((long)(bm0 + rt)) << 9) + glog * 8,
                    lds + chunk * 512);                     // bufA0
    }
    VMCNT(4);   // B(0) regs ready (A-dma may remain in flight)
#pragma unroll
    for (int p = 0; p < 8; ++p) {
        const int rt = p * 16 + brow;
        const int bchunk = rt >> 3;
        const int brs = rt & 7;
        short4 o;
        o.x = f2bf_fast(v[p].x);
        o.y = f2bf_fast(v[p].y);
        o.z = f2bf_fast(v[p].z);
        o.w = f2bf_fast(v[p].w);
        *(short4*)(lds + 8192 + bchunk * 512 + brs * 64 + ((bg ^ brs) * 8) + bh * 4) = o;
    }
    LGKM0;

    for (int kt = 0; kt < 8; ++kt) {
        short* bufc = lds + (kt & 1) * 16384;
        short* bufn = lds + ((kt + 1) & 1) * 16384;

        if (kt < 7) {
            const int k0n = (kt + 1) * 64;
            // issue next B reg-loads (8 vm) + next A dma (4 vm)
#pragma unroll
            for (int p = 0; p < 8; ++p) {
                const int rt = p * 16 + brow;
                v[p] = *(const float4*)(Xs + (((long)(bn0 + rt)) << 9) + k0n + col4 * 4);
            }
#pragma unroll
            for (int i = 0; i < 4; ++i) {
                const int chunk = w * 4 + i;
                const int rt = chunk * 8 + rsub;
                gload_lds16(A + (((long)(bm0 + rt)) << 9) + k0n + glog * 8,
                            bufn + chunk * 512);
            }
            VMCNT(12);   // drain everything older than this iter's 12 issues
        } else {
            VMCNT(0);
        }
        BARRIER;         // bufc (A dma + B writes) visible to all waves
        FENCE;

        {
            short* ldsA = bufc;
            short* ldsB = bufc + 8192;
#pragma unroll
            for (int kk = 0; kk < 2; ++kk) {
                const int c = kk * 4 + q;
                const int goff = ((c ^ (r & 7)) * 8);
                short8 af[4], bfr[4];
#pragma unroll
                for (int i = 0; i < 4; ++i) {
                    af[i]  = *(const short8*)(ldsA + (wm0 + i * 16 + r) * 64 + goff);
                    bfr[i] = *(const short8*)(ldsB + (wn0 + i * 16 + r) * 64 + goff);
                }
#pragma unroll
                for (int i = 0; i < 4; ++i)
#pragma unroll
                    for (int j = 0; j < 4; ++j)
                        acc[i][j] = __builtin_amdgcn_mfma_f32_16x16x32_bf16(
                            af[i], bfr[j], acc[i][j], 0, 0, 0);
            }
        }

        FENCE;           // keep ds_reads above this barrier
        BARRIER;         // all waves done reading bufc; safe to overwrite next iter

        if (kt < 7) {
            VMCNT(4);    // next-tile B regs ready (next A-dma may remain)
#pragma unroll
            for (int p = 0; p < 8; ++p) {
                const int rt = p * 16 + brow;
                const int bchunk = rt >> 3;
                const int brs = rt & 7;
                short4 o;
                o.x = f2bf_fast(v[p].x);
                o.y = f2bf_fast(v[p].y);
                o.z = f2bf_fast(v[p].z);
                o.w = f2bf_fast(v[p].w);
                *(short4*)(bufn + 8192 + bchunk * 512 + brs * 64 + ((bg ^ brs) * 8) + bh * 4) = o;
            }
            LGKM0;       // ds_writes landed before next iter's barrier
        }
    }

    // ---- epilogue: stage C tile in LDS, then 256B-coalesced stores ----
    // [128][132] shorts (pad 4 -> write-side conflict-free, read ~4-way mild)
    // 33792 B fits in the 64 KB lds (both K-buffers are dead now).
    {
        short* cst = lds;
#pragma unroll
        for (int i = 0; i < 4; ++i) {
            const int rl = wm0 + i * 16 + q * 4;
#pragma unroll
            for (int j = 0; j < 4; ++j) {
                const int cl = wn0 + j * 16 + r;
#pragma unroll
                for (int rg = 0; rg < 4; ++rg)
                    cst[(rl + rg) * 132 + cl] = f2bf(acc[i][j][rg]);
            }
        }
        __syncthreads();
        const int orow = t >> 4;           // 0..15
        const int ocol = (t & 15) * 8;     // short8 column
#pragma unroll
        for (int it = 0; it < 8; ++it) {
            const int rr = it * 16 + orow;
            short8 vv = *(const short8*)(cst + rr * 132 + ocol);
            *(short8*)(Tt + (long)(bm0 + rr) * N512 + bn0 + ocol) = vv;
        }
    }
}

// ---------------------------------------------------------------------------
// Stage 2: Out[z][m][n] = sum_h M[m,h] * Tt[z][n,h]  (both bf16, fp32 out)
// Same 2-phase dbuf pipeline; both operands via global_load_lds DMA.
// fp32 direct stores are 64B segments -> no RMW; at roofline, leave alone.
// ---------------------------------------------------------------------------
__global__ __launch_bounds__(256) void gemm_s2(const short* __restrict__ A,
                                               const short* __restrict__ Bg,
                                               float* __restrict__ Cg) {
    __shared__ __align__(16) short lds[4 * 8192];

    const int t = threadIdx.x;
    const int w = t >> 6;
    const int l = t & 63;
    const int q = (t >> 4) & 3;
    const int r = t & 15;

    const int bm0 = blockIdx.y * 128;
    const int bn0 = blockIdx.x * 128;
    const int wm0 = (w >> 1) * 64;
    const int wn0 = (w & 1) * 64;

    const short* Bs = Bg + ((long)blockIdx.z << 18);
    float* C = Cg + ((long)blockIdx.z << 18);

    const int rsub = l >> 3;
    const int glog = (l & 7) ^ rsub;

    floatx4 acc[4][4] = {};

    // ---- prologue: stage tile 0 (8 dma) ----
#pragma unroll
    for (int i = 0; i < 4; ++i) {
        const int chunk = w * 4 + i;
        const int rt = chunk * 8 + rsub;
        gload_lds16(A + (((long)(bm0 + rt)) << 9) + glog * 8,
                    lds + chunk * 512);
        gload_lds16(Bs + (((long)(bn0 + rt)) << 9) + glog * 8,
                    lds + 8192 + chunk * 512);
    }

    for (int kt = 0; kt < 8; ++kt) {
        short* bufc = lds + (kt & 1) * 16384;
        short* bufn = lds + ((kt + 1) & 1) * 16384;

        if (kt < 7) {
            const int k0n = (kt + 1) * 64;
#pragma unroll
            for (int i = 0; i < 4; ++i) {
                const int chunk = w * 4 + i;
                const int rt = chunk * 8 + rsub;
                gload_lds16(A + (((long)(bm0 + rt)) << 9) + k0n + glog * 8,
                            bufn + chunk * 512);
                gload_lds16(Bs + (((long)(bn0 + rt)) << 9) + k0n + glog * 8,
                            bufn + 8192 + chunk * 512);
            }
            VMCNT(8);    // drain previous tile's dma; this iter's 8 stay in flight
        } else {
            VMCNT(0);
        }
        BARRIER;
        FENCE;

        {
            short* ldsA = bufc;
            short* ldsB = bufc + 8192;
#pragma unroll
            for (int kk = 0; kk < 2; ++kk) {
                const int c = kk * 4 + q;
                const int goff = ((c ^ (r & 7)) * 8);
                short8 af[4], bfr[4];
#pragma unroll
                for (int i = 0; i < 4; ++i) {
                    af[i]  = *(const short8*)(ldsA + (wm0 + i * 16 + r) * 64 + goff);
                    bfr[i] = *(const short8*)(ldsB + (wn0 + i * 16 + r) * 64 + goff);
                }
#pragma unroll
                for (int i = 0; i < 4; ++i)
#pragma unroll
                    for (int j = 0; j < 4; ++j)
                        acc[i][j] = __builtin_amdgcn_mfma_f32_16x16x32_bf16(
                            af[i], bfr[j], acc[i][j], 0, 0, 0);
            }
        }

        FENCE;
        BARRIER;
    }

#pragma unroll
    for (int i = 0; i < 4; ++i) {
        const int mrow = bm0 + wm0 + i * 16 + q * 4;
#pragma unroll
        for (int j = 0; j < 4; ++j) {
            const int ncol = bn0 + wn0 + j * 16 + r;
#pragma unroll
            for (int rg = 0; rg < 4; ++rg)
                C[(long)(mrow + rg) * N512 + ncol] = acc[i][j][rg];
        }
    }
}

extern "C" void kernel_launch(void* const* d_in, const int* in_sizes, int n_in,
                              void* d_out, int out_size, void* d_ws, size_t ws_size,
                              hipStream_t stream) {
    const float* X = (const float*)d_in[0];
    float* out = (float*)d_out;

    const long plane = (long)N512 * N512;          // 262144
    const int slices = in_sizes[0] / (int)plane;   // 96

    short* Mb = (short*)d_ws;                      // 512 KB
    short* Tt = Mb + plane;                        // chunk * plane bf16

    long avail = (long)ws_size - plane * 2;        // bytes after M
    int chunk = (int)(avail / (plane * 2));        // bf16 plane per slice
    if (chunk > slices) chunk = slices;
    // snap: multiple of 32 (full 512-block scheduling rounds), else even
    // (keeps the s1 XCD-sibling decode exact).
    if (chunk >= 32) chunk &= ~31;
    else if (chunk >= 2) chunk &= ~1;
    if (chunk < 1) chunk = 1;

    build_idct_matrix_bf16<<<dim3((int)(plane / 256)), dim3(256), 0, stream>>>(Mb);

    for (int s0 = 0; s0 < slices; s0 += chunk) {
        int c = (s0 + chunk <= slices) ? chunk : (slices - s0);
        // stage 1 (reads fp32 X directly): Tt[z][n][h] = sum_k M[n,k]*X[z][h,k]
        gemm_s1<<<dim3(16 * c), dim3(256), 0, stream>>>(
            Mb, X + (long)s0 * plane, Tt);
        // stage 2: Out[z][m][n] = sum_h M[m,h]*Tt[z][n,h]
        gemm_s2<<<dim3(4, 4, c), dim3(256), 0, stream>>>(
            Mb, Tt, out + (long)s0 * plane);
    }
}